// Round 8
// baseline (170.561 us; speedup 1.0000x reference)
//
#include <hip/hip_runtime.h>

// Problem constants (from reference)
#define BATCH 2048
#define FDIM  1024
#define GTILE 16
#define F4    (FDIM / 4)                  // 256 float4 col-groups per row
#define CHUNKS 128
#define ROWS_PER_CHUNK (BATCH / CHUNKS)   // 16

// ws layout (in floats):
#define OFF_P1   0                        // [CHUNKS][FDIM] partial col sums of xf (512 KB)
#define OFF_SACC 131072                   // [FDIM] atomic accum: relu sums
#define OFF_QACC 132096                   // [FDIM] atomic accum: relu sumsq
#define OFF_MEAN 133120                   // [FDIM]
#define OFF_SC   134144                   // [FDIM] scale = wp/sd
#define OFF_CC   135168                   // [FDIM] mu*scale
#define OFF_CNT  136192                   // int counter (1)

__device__ __forceinline__ void v4add(float4& a, const float4& b) {
    a.x += b.x; a.y += b.y; a.z += b.z; a.w += b.w;
}

// 128 blocks x 256 threads, coalesced partial column sums.
// Block 0 additionally zero-inits the atomic accumulators + ticket counter
// (ws is re-poisoned to 0xAA before every launch).
__global__ void k1_partial_sum(const float4* __restrict__ xf,
                               float4* __restrict__ p1,
                               float* __restrict__ sacc,
                               float* __restrict__ qacc,
                               int* __restrict__ counter) {
    const int tid = threadIdx.x;            // col-group
    const int chunk = blockIdx.x;           // 0..127
    if (chunk == 0) {
        // zero 2*1024 floats + counter
        sacc[tid] = 0.f; sacc[tid + 256] = 0.f; sacc[tid + 512] = 0.f; sacc[tid + 768] = 0.f;
        qacc[tid] = 0.f; qacc[tid + 256] = 0.f; qacc[tid + 512] = 0.f; qacc[tid + 768] = 0.f;
        if (tid == 0) *counter = 0;
    }
    const float4* p = xf + (size_t)chunk * ROWS_PER_CHUNK * F4 + tid;
    float4 s = {0.f, 0.f, 0.f, 0.f};
#pragma unroll
    for (int r = 0; r < ROWS_PER_CHUNK; ++r) v4add(s, p[r * F4]);
    p1[chunk * F4 + tid] = s;
}

// 128 blocks x 256 threads. Each block: redundant coalesced p1-reduce -> mean
// (identical fp32 result in every block), relu sum/sumsq over its 16 rows,
// atomic accumulate into sacc/qacc, then last-block ticket finalizes
// mean/sc/cc from the 8 KB accumulators.
__global__ void k2_relu_stats(const float4* __restrict__ xf,
                              const float* __restrict__ wp,
                              const float4* __restrict__ p1,
                              float* __restrict__ sacc,
                              float* __restrict__ qacc,
                              float4* __restrict__ mean,
                              float4* __restrict__ sc,
                              float4* __restrict__ cc,
                              int* __restrict__ counter) {
    const int tid = threadIdx.x;
    const int chunk = blockIdx.x;
    __shared__ int isLast;

    // Redundant p1 reduce (coalesced, L2-shared): mean of col-group tid.
    float4 m = {0.f, 0.f, 0.f, 0.f};
#pragma unroll 8
    for (int c = 0; c < CHUNKS; ++c) v4add(m, p1[c * F4 + tid]);
    const float inv_n = 1.0f / (float)BATCH;
    m.x *= inv_n; m.y *= inv_n; m.z *= inv_n; m.w *= inv_n;

    // relu(x - mean) sum & sumsq over this block's 16 rows (coalesced).
    const float4* p = xf + (size_t)chunk * ROWS_PER_CHUNK * F4 + tid;
    float4 s = {0.f, 0.f, 0.f, 0.f};
    float4 q = {0.f, 0.f, 0.f, 0.f};
#pragma unroll
    for (int r = 0; r < ROWS_PER_CHUNK; ++r) {
        float4 v = p[r * F4];
        float rx = fmaxf(v.x - m.x, 0.f);
        float ry = fmaxf(v.y - m.y, 0.f);
        float rz = fmaxf(v.z - m.z, 0.f);
        float rw = fmaxf(v.w - m.w, 0.f);
        s.x += rx; s.y += ry; s.z += rz; s.w += rw;
        q.x += rx * rx; q.y += ry * ry; q.z += rz * rz; q.w += rw * rw;
    }
    // Accumulate into global (device-scope float atomics; 128 adds/address).
    atomicAdd(&sacc[tid * 4 + 0], s.x); atomicAdd(&sacc[tid * 4 + 1], s.y);
    atomicAdd(&sacc[tid * 4 + 2], s.z); atomicAdd(&sacc[tid * 4 + 3], s.w);
    atomicAdd(&qacc[tid * 4 + 0], q.x); atomicAdd(&qacc[tid * 4 + 1], q.y);
    atomicAdd(&qacc[tid * 4 + 2], q.z); atomicAdd(&qacc[tid * 4 + 3], q.w);

    __threadfence();            // release: atomics + stores visible device-wide
    __syncthreads();            // whole block done accumulating
    if (tid == 0) {
        int old = atomicAdd(counter, 1);
        isLast = (old == CHUNKS - 1);
    }
    __syncthreads();
    if (!isLast) return;
    __threadfence();            // acquire: see all other blocks' accumulations

    // Last block: 8 KB read, finalize. Thread t owns col-group t.
    float4 S, Q;
    S.x = sacc[tid * 4 + 0]; S.y = sacc[tid * 4 + 1];
    S.z = sacc[tid * 4 + 2]; S.w = sacc[tid * 4 + 3];
    Q.x = qacc[tid * 4 + 0]; Q.y = qacc[tid * 4 + 1];
    Q.z = qacc[tid * 4 + 2]; Q.w = qacc[tid * 4 + 3];
    const float w = wp[0];
    float4 scale, cmb;
    float mu, var;
    mu = S.x * inv_n; var = (Q.x - S.x * mu) / (float)(BATCH - 1);
    scale.x = w * rsqrtf(var); cmb.x = mu * scale.x;
    mu = S.y * inv_n; var = (Q.y - S.y * mu) / (float)(BATCH - 1);
    scale.y = w * rsqrtf(var); cmb.y = mu * scale.y;
    mu = S.z * inv_n; var = (Q.z - S.z * mu) / (float)(BATCH - 1);
    scale.z = w * rsqrtf(var); cmb.z = mu * scale.z;
    mu = S.w * inv_n; var = (Q.w - S.w * mu) / (float)(BATCH - 1);
    scale.w = w * rsqrtf(var); cmb.w = mu * scale.w;
    mean[tid] = m;
    sc[tid]   = scale;
    cc[tid]   = cmb;
}

__global__ void k4_write(const float4* __restrict__ xf,
                         const float4* __restrict__ mean,
                         const float4* __restrict__ sc,
                         const float4* __restrict__ cc,
                         float4* __restrict__ out) {
    const int tid = threadIdx.x;     // 0..255
    const int row = blockIdx.x;      // 0..2047
    float4 m = mean[tid];
    float4 a = sc[tid];
    float4 c = cc[tid];
    float4 v = xf[(size_t)row * F4 + tid];
    float4 o;
    o.x = fmaxf(v.x - m.x, 0.f) * a.x - c.x;
    o.y = fmaxf(v.y - m.y, 0.f) * a.y - c.y;
    o.z = fmaxf(v.z - m.z, 0.f) * a.z - c.z;
    o.w = fmaxf(v.w - m.w, 0.f) * a.w - c.w;
    float4* dst = out + (size_t)row * (GTILE * F4) + tid;
#pragma unroll
    for (int g = 0; g < GTILE; ++g) {
        dst[g * F4] = o;
    }
}

extern "C" void kernel_launch(void* const* d_in, const int* in_sizes, int n_in,
                              void* d_out, int out_size, void* d_ws, size_t ws_size,
                              hipStream_t stream) {
    const float4* xf4 = (const float4*)d_in[0];
    const float* wp = (const float*)d_in[1];
    float* ws = (float*)d_ws;
    float4* out = (float4*)d_out;

    float4* p1   = (float4*)(ws + OFF_P1);
    float* sacc  = ws + OFF_SACC;
    float* qacc  = ws + OFF_QACC;
    float4* mean = (float4*)(ws + OFF_MEAN);
    float4* sc   = (float4*)(ws + OFF_SC);
    float4* cc   = (float4*)(ws + OFF_CC);
    int* counter = (int*)(ws + OFF_CNT);

    k1_partial_sum<<<CHUNKS, 256, 0, stream>>>(xf4, p1, sacc, qacc, counter);
    k2_relu_stats<<<CHUNKS, 256, 0, stream>>>(xf4, wp, p1, sacc, qacc, mean, sc, cc, counter);
    k4_write<<<BATCH, 256, 0, stream>>>(xf4, mean, sc, cc, out);
}

// Round 9
// 154.657 us; speedup vs baseline: 1.1028x; 1.1028x over previous
//
#include <hip/hip_runtime.h>

// Problem constants (from reference)
#define BATCH 2048
#define FDIM  1024
#define GTILE 16
#define F4    (FDIM / 4)                  // 256 float4 col-groups per row
#define CHUNKS 128
#define ROWS_PER_CHUNK (BATCH / CHUNKS)   // 16

// ws layout (in floats):
#define OFF_P1   0                        // [CHUNKS][FDIM] partial col sums of xf
#define OFF_P2S  131072                   // [CHUNKS][FDIM] partial col sums of relu(xf-mean)
#define OFF_P2Q  262144                   // [CHUNKS][FDIM] partial col sumsq
#define OFF_MEAN 393216                   // [FDIM]
#define OFF_SC   394240                   // [FDIM] scale = wp/sd
#define OFF_CC   395264                   // [FDIM] mu*scale

__device__ __forceinline__ void v4add(float4& a, const float4& b) {
    a.x += b.x; a.y += b.y; a.z += b.z; a.w += b.w;
}

__global__ void k1_partial_sum(const float4* __restrict__ xf, float4* __restrict__ p1) {
    const int tid = threadIdx.x;            // col-group
    const int chunk = blockIdx.x;           // 0..127
    const float4* p = xf + (size_t)chunk * ROWS_PER_CHUNK * F4 + tid;
    float4 s = {0.f, 0.f, 0.f, 0.f};
#pragma unroll
    for (int r = 0; r < ROWS_PER_CHUNK; ++r) v4add(s, p[r * F4]);
    p1[chunk * F4 + tid] = s;
}

__global__ void k2_relu_partial(const float4* __restrict__ xf,
                                const float4* __restrict__ p1,
                                float4* __restrict__ p2s,
                                float4* __restrict__ p2q) {
    const int tid = threadIdx.x;
    const int chunk = blockIdx.x;
    // Redundant coalesced p1 reduce (L2-shared) -> mean of col-group tid.
    float4 m = {0.f, 0.f, 0.f, 0.f};
#pragma unroll 8
    for (int c = 0; c < CHUNKS; ++c) v4add(m, p1[c * F4 + tid]);
    const float inv_n = 1.0f / (float)BATCH;
    m.x *= inv_n; m.y *= inv_n; m.z *= inv_n; m.w *= inv_n;

    const float4* p = xf + (size_t)chunk * ROWS_PER_CHUNK * F4 + tid;
    float4 s = {0.f, 0.f, 0.f, 0.f};
    float4 q = {0.f, 0.f, 0.f, 0.f};
#pragma unroll
    for (int r = 0; r < ROWS_PER_CHUNK; ++r) {
        float4 v = p[r * F4];
        float rx = fmaxf(v.x - m.x, 0.f);
        float ry = fmaxf(v.y - m.y, 0.f);
        float rz = fmaxf(v.z - m.z, 0.f);
        float rw = fmaxf(v.w - m.w, 0.f);
        s.x += rx; s.y += ry; s.z += rz; s.w += rw;
        q.x += rx * rx; q.y += ry * ry; q.z += rz * rz; q.w += rw * rw;
    }
    p2s[chunk * F4 + tid] = s;
    p2q[chunk * F4 + tid] = q;
}

// 16 blocks x 256 threads. Block b owns col-groups [b*16, b*16+16).
// Thread t: cg = b*16 + (t&15), slice = t>>4 -> 8 chunks. Coalesced loads,
// LDS tree over the 16 slices.
__global__ void k3_finalize(const float* __restrict__ wp,
                            const float4* __restrict__ p1,
                            const float4* __restrict__ p2s,
                            const float4* __restrict__ p2q,
                            float4* __restrict__ mean,
                            float4* __restrict__ sc,
                            float4* __restrict__ cc) {
    __shared__ float4 rm[256], rs[256], rq[256];   // 12 KB
    const int t = threadIdx.x;
    const int b = blockIdx.x;                      // 0..15
    const int cg = b * 16 + (t & 15);              // col-group
    const int slice = t >> 4;                      // 0..15
    const int c0 = slice * (CHUNKS / 16);          // 8 chunks per slice
    float4 m = {0.f,0.f,0.f,0.f}, s = {0.f,0.f,0.f,0.f}, q = {0.f,0.f,0.f,0.f};
#pragma unroll
    for (int c = c0; c < c0 + CHUNKS / 16; ++c) {
        v4add(m, p1[c * F4 + cg]);
        v4add(s, p2s[c * F4 + cg]);
        v4add(q, p2q[c * F4 + cg]);
    }
    rm[t] = m; rs[t] = s; rq[t] = q;
    __syncthreads();
    for (int off = 128; off >= 16; off >>= 1) {
        if (t < off) { v4add(rm[t], rm[t + off]); v4add(rs[t], rs[t + off]); v4add(rq[t], rq[t + off]); }
        __syncthreads();
    }
    if (t < 16) {
        const float inv_n = 1.0f / (float)BATCH;
        const float w = wp[0];
        float4 M = rm[t], S = rs[t], Q = rq[t];
        float4 mn, scale, cmb;
        float mu, var;
        mn.x = M.x * inv_n;
        mu = S.x * inv_n; var = (Q.x - S.x * mu) / (float)(BATCH - 1);
        scale.x = w * rsqrtf(var); cmb.x = mu * scale.x;
        mn.y = M.y * inv_n;
        mu = S.y * inv_n; var = (Q.y - S.y * mu) / (float)(BATCH - 1);
        scale.y = w * rsqrtf(var); cmb.y = mu * scale.y;
        mn.z = M.z * inv_n;
        mu = S.z * inv_n; var = (Q.z - S.z * mu) / (float)(BATCH - 1);
        scale.z = w * rsqrtf(var); cmb.z = mu * scale.z;
        mn.w = M.w * inv_n;
        mu = S.w * inv_n; var = (Q.w - S.w * mu) / (float)(BATCH - 1);
        scale.w = w * rsqrtf(var); cmb.w = mu * scale.w;
        mean[b * 16 + t] = mn;
        sc[b * 16 + t]   = scale;
        cc[b * 16 + t]   = cmb;
    }
}

// 1024 blocks x 256 threads: 2 rows per block, loads issued up front.
__global__ void __launch_bounds__(256) k4_write(const float4* __restrict__ xf,
                                                const float4* __restrict__ mean,
                                                const float4* __restrict__ sc,
                                                const float4* __restrict__ cc,
                                                float4* __restrict__ out) {
    const int tid = threadIdx.x;          // 0..255
    const int row0 = blockIdx.x * 2;      // 0..2046
    float4 v0 = xf[(size_t)row0 * F4 + tid];
    float4 v1 = xf[(size_t)(row0 + 1) * F4 + tid];
    float4 m = mean[tid];
    float4 a = sc[tid];
    float4 c = cc[tid];
    float4 o0, o1;
    o0.x = fmaxf(v0.x - m.x, 0.f) * a.x - c.x;
    o0.y = fmaxf(v0.y - m.y, 0.f) * a.y - c.y;
    o0.z = fmaxf(v0.z - m.z, 0.f) * a.z - c.z;
    o0.w = fmaxf(v0.w - m.w, 0.f) * a.w - c.w;
    o1.x = fmaxf(v1.x - m.x, 0.f) * a.x - c.x;
    o1.y = fmaxf(v1.y - m.y, 0.f) * a.y - c.y;
    o1.z = fmaxf(v1.z - m.z, 0.f) * a.z - c.z;
    o1.w = fmaxf(v1.w - m.w, 0.f) * a.w - c.w;
    float4* dst0 = out + (size_t)row0 * (GTILE * F4) + tid;
    float4* dst1 = dst0 + (GTILE * F4);
#pragma unroll
    for (int g = 0; g < GTILE; ++g) {
        dst0[g * F4] = o0;
        dst1[g * F4] = o1;
    }
}

extern "C" void kernel_launch(void* const* d_in, const int* in_sizes, int n_in,
                              void* d_out, int out_size, void* d_ws, size_t ws_size,
                              hipStream_t stream) {
    const float4* xf4 = (const float4*)d_in[0];
    const float* wp = (const float*)d_in[1];
    float* ws = (float*)d_ws;
    float4* out = (float4*)d_out;

    float4* p1   = (float4*)(ws + OFF_P1);
    float4* p2s  = (float4*)(ws + OFF_P2S);
    float4* p2q  = (float4*)(ws + OFF_P2Q);
    float4* mean = (float4*)(ws + OFF_MEAN);
    float4* sc   = (float4*)(ws + OFF_SC);
    float4* cc   = (float4*)(ws + OFF_CC);

    k1_partial_sum<<<CHUNKS, 256, 0, stream>>>(xf4, p1);
    k2_relu_partial<<<CHUNKS, 256, 0, stream>>>(xf4, p1, p2s, p2q);
    k3_finalize<<<16, 256, 0, stream>>>(wp, p1, p2s, p2q, mean, sc, cc);
    k4_write<<<BATCH / 2, 256, 0, stream>>>(xf4, mean, sc, cc, out);
}